// Round 12
// baseline (275.414 us; speedup 1.0000x reference)
//
#include <hip/hip_runtime.h>
#include <hip/hip_bf16.h>

typedef unsigned short u16;
typedef unsigned long long u64;
typedef __bf16 bf16x8 __attribute__((ext_vector_type(8)));
typedef float f32x4 __attribute__((ext_vector_type(4)));
typedef float f32x16 __attribute__((ext_vector_type(16)));
typedef unsigned u32x4 __attribute__((ext_vector_type(4)));

#define DIM 1024
#define NH 16
#define HD 64
// 0.125 * log2(e): folds the 1/sqrt(64) score scale and the exp->exp2 change of base
#define QSCALE 0.180336880972788f

__device__ __forceinline__ u16 f2bf(float f) {
  union { float f; unsigned u; } v; v.f = f;
  unsigned r = v.u + 0x7fffu + ((v.u >> 16) & 1u);
  return (u16)(r >> 16);
}

__device__ __forceinline__ unsigned pk2(float a, float b) {
  union { __hip_bfloat162 h; unsigned u; } cv;
  cv.h = __float22bfloat162_rn(make_float2(a, b));
  return cv.u;
}

__device__ __forceinline__ float bf2f(unsigned s) {
  union { unsigned u; float f; } v; v.u = s << 16; return v.f;
}

__device__ __forceinline__ float fexp2(float x) {
#if __has_builtin(__builtin_amdgcn_exp2f)
  return __builtin_amdgcn_exp2f(x);   // raw v_exp_f32, no OCML denormal fixup
#else
  return exp2f(x);
#endif
}

__device__ __forceinline__ void gld16(const u16* gp, u16* lp) {
  __builtin_amdgcn_global_load_lds(
      (const __attribute__((address_space(1))) unsigned int*)(const void*)gp,
      (__attribute__((address_space(3))) unsigned int*)(void*)lp, 16, 0, 0);
}

// swap: a.hi-lanes <-> b.lo-lanes.  After: a = {lo: a, hi: b[lane-32]}, b = {lo: a[lane+32], hi: b}
__device__ __forceinline__ void pl32swap(unsigned& a, unsigned& b) {
  asm volatile("v_permlane32_swap_b32 %0, %1" : "+v"(a), "+v"(b));
}

__device__ __forceinline__ void drain_vm_barrier() {
  // counted-drain of our prefetch, then RAW barrier (no compiler-injected full drain)
  asm volatile("s_waitcnt vmcnt(0)" ::: "memory");
  __builtin_amdgcn_s_barrier();
}

// ---------------- Fused prep: 2x LayerNorm + 4x weight transpose ----------------
__global__ __launch_bounds__(256) void prep_kernel(
    const float* __restrict__ q, const float* __restrict__ c,
    const float* __restrict__ gq, const float* __restrict__ bq,
    const float* __restrict__ gkv, const float* __restrict__ bkv,
    u16* __restrict__ qn, u16* __restrict__ cn,
    const float* W0, const float* W1, const float* W2, const float* W3,
    u16* O0, u16* O1, u16* O2, u16* O3) {
  __shared__ float red[2][4];
  __shared__ float t[32][33];
  int bid = blockIdx.x, tid = threadIdx.x;
  if (bid < 8192) {
    const float* x  = bid < 4096 ? q : c;
    const float* g  = bid < 4096 ? gq : gkv;
    const float* be = bid < 4096 ? bq : bkv;
    u16* out = bid < 4096 ? qn : cn;
    int row = bid & 4095;
    float4 v = ((const float4*)(x + (size_t)row * DIM))[tid];
    float s1 = v.x + v.y + v.z + v.w;
    float s2 = v.x * v.x + v.y * v.y + v.z * v.z + v.w * v.w;
#pragma unroll
    for (int o = 32; o >= 1; o >>= 1) { s1 += __shfl_xor(s1, o, 64); s2 += __shfl_xor(s2, o, 64); }
    int wv = tid >> 6;
    if ((tid & 63) == 0) { red[0][wv] = s1; red[1][wv] = s2; }
    __syncthreads();
    s1 = red[0][0] + red[0][1] + red[0][2] + red[0][3];
    s2 = red[1][0] + red[1][1] + red[1][2] + red[1][3];
    float mu = s1 * (1.f / DIM);
    float var = s2 * (1.f / DIM) - mu * mu;
    float rs = rsqrtf(var + 1e-5f);
    float4 gv = ((const float4*)g)[tid];
    float4 bv = ((const float4*)be)[tid];
    uint2 o2;
    o2.x = pk2((v.x - mu) * rs * gv.x + bv.x, (v.y - mu) * rs * gv.y + bv.y);
    o2.y = pk2((v.z - mu) * rs * gv.z + bv.z, (v.w - mu) * rs * gv.w + bv.w);
    ((uint2*)(out + (size_t)row * DIM))[tid] = o2;
  } else {
    int wid = bid - 8192;
    int z = wid >> 10;
    const float* W = z == 0 ? W0 : z == 1 ? W1 : z == 2 ? W2 : W3;
    u16* O        = z == 0 ? O0 : z == 1 ? O1 : z == 2 ? O2 : O3;
    int xy = wid & 1023;
    int bx = (xy & 31) * 32, by = (xy >> 5) * 32;
    int tx = tid & 31, ty = tid >> 5;
#pragma unroll
    for (int i = 0; i < 4; ++i) t[ty + i * 8][tx] = W[(size_t)(by + ty + i * 8) * DIM + bx + tx];
    __syncthreads();
#pragma unroll
    for (int i = 0; i < 4; ++i) O[(size_t)(bx + ty + i * 8) * DIM + by + tx] = f2bf(t[tx][ty + i * 8]);
  }
}

// ---------------- QKV projections: z=0 fused K+V (shared A tile), z=1 Q ----------------
// Double-buffered LDS (2x32KB) + prefetch-overlap: STAGE(t+1) issued BEFORE compute(t),
// single vmcnt(0)+raw-barrier per K-tile (T3-minimum). Round-2 epilogues.
#define QKV_BUF 16384  // u16 per buffer: (128+64+64)*64
__global__ __launch_bounds__(256) void gemm_qkv(
    const u16* __restrict__ qn, const u16* __restrict__ cn,
    const u16* __restrict__ Wqt, const u16* __restrict__ Wkt, const u16* __restrict__ Wvt,
    const float* __restrict__ bq, const float* __restrict__ bk, const float* __restrict__ bv,
    u16* __restrict__ Qb, u16* __restrict__ Kb, u16* __restrict__ Vtb) {
  __shared__ __align__(16) u16 sm[2 * QKV_BUF];  // 64 KB
  int tid = threadIdx.x, wave = tid >> 6, lane = tid & 63;
  int lr = lane & 15, quad = lane >> 4;
  int m0 = blockIdx.x * 128, n0 = blockIdx.y * 64;
  int wm = (wave >> 1) * 64, wn = (wave & 1) * 32;

  if (blockIdx.z == 0) {
    // ---- K + V fused over A = cn ----
    auto stage = [&](int buf, int kt) {
      u16* As  = sm + buf * QKV_BUF;
      u16* B0s = As + 128 * 64;
      u16* B1s = As + 192 * 64;
#pragma unroll
      for (int r = 0; r < 4; ++r) {
        int slot = tid + r * 256;
        int row = slot >> 3;
        int c = (slot & 7) ^ (row & 7);
        gld16(cn + (size_t)(m0 + row) * DIM + kt + c * 8, &As[slot * 8]);
      }
#pragma unroll
      for (int r = 0; r < 2; ++r) {
        int slot = tid + r * 256;
        int row = slot >> 3;
        int c = (slot & 7) ^ (row & 7);
        gld16(Wkt + (size_t)(n0 + row) * DIM + kt + c * 8, &B0s[slot * 8]);
        gld16(Wvt + (size_t)(n0 + row) * DIM + kt + c * 8, &B1s[slot * 8]);
      }
    };

    f32x4 acck[4][2] = {}, accv[4][2] = {};
    stage(0, 0);
    drain_vm_barrier();
    int cur = 0;
    for (int kt = 0; kt < DIM; kt += 64) {
      if (kt + 64 < DIM) stage(cur ^ 1, kt + 64);
      const u16* As  = sm + cur * QKV_BUF;
      const u16* B0s = As + 128 * 64;
      const u16* B1s = As + 192 * 64;
#pragma unroll
      for (int kc = 0; kc < 2; ++kc) {
        int pc = ((kc * 4 + quad) ^ (lr & 7)) * 8;
        bf16x8 af[4], b0f[2], b1f[2];
#pragma unroll
        for (int i = 0; i < 4; ++i) af[i] = *(const bf16x8*)&As[(wm + i * 16 + lr) * 64 + pc];
#pragma unroll
        for (int j = 0; j < 2; ++j) {
          b0f[j] = *(const bf16x8*)&B0s[(wn + j * 16 + lr) * 64 + pc];
          b1f[j] = *(const bf16x8*)&B1s[(wn + j * 16 + lr) * 64 + pc];
        }
#pragma unroll
        for (int mi = 0; mi < 4; ++mi)
#pragma unroll
          for (int ni = 0; ni < 2; ++ni) {
            acck[mi][ni] = __builtin_amdgcn_mfma_f32_16x16x32_bf16(af[mi], b0f[ni], acck[mi][ni], 0, 0, 0);
            accv[mi][ni] = __builtin_amdgcn_mfma_f32_16x16x32_bf16(b1f[ni], af[mi], accv[mi][ni], 0, 0, 0);
          }
      }
      drain_vm_barrier();
      cur ^= 1;
    }
    // K epilogue: row-major
#pragma unroll
    for (int mi = 0; mi < 4; ++mi)
#pragma unroll
      for (int ni = 0; ni < 2; ++ni) {
        int col = n0 + wn + ni * 16 + lr;
        float bb_ = bk[col];
        int row0 = m0 + wm + mi * 16 + quad * 4;
#pragma unroll
        for (int r = 0; r < 4; ++r)
          Kb[(size_t)(row0 + r) * DIM + col] = f2bf(acck[mi][ni][r] + bb_);
      }
    // V epilogue: accv = C^T (col=token m via lr, row=channel n via quad*4+r)
#pragma unroll
    for (int mi = 0; mi < 4; ++mi) {
      int m = m0 + wm + mi * 16 + lr;
      int bb = m >> 11, tt = m & 2047;
      u16* outb = Vtb + (((size_t)bb << 10)) * 2048 + tt;
#pragma unroll
      for (int ni = 0; ni < 2; ++ni) {
        int nbase = n0 + wn + ni * 16 + quad * 4;
#pragma unroll
        for (int r = 0; r < 4; ++r)
          outb[(size_t)(nbase + r) * 2048] = f2bf(accv[mi][ni][r] + bv[nbase + r]);
      }
    }
  } else {
    // ---- Q over A = qn ----
    auto stage = [&](int buf, int kt) {
      u16* As  = sm + buf * QKV_BUF;
      u16* B0s = As + 128 * 64;
#pragma unroll
      for (int r = 0; r < 4; ++r) {
        int slot = tid + r * 256;
        int row = slot >> 3;
        int c = (slot & 7) ^ (row & 7);
        gld16(qn + (size_t)(m0 + row) * DIM + kt + c * 8, &As[slot * 8]);
      }
#pragma unroll
      for (int r = 0; r < 2; ++r) {
        int slot = tid + r * 256;
        int row = slot >> 3;
        int c = (slot & 7) ^ (row & 7);
        gld16(Wqt + (size_t)(n0 + row) * DIM + kt + c * 8, &B0s[slot * 8]);
      }
    };

    f32x4 acc[4][2] = {};
    stage(0, 0);
    drain_vm_barrier();
    int cur = 0;
    for (int kt = 0; kt < DIM; kt += 64) {
      if (kt + 64 < DIM) stage(cur ^ 1, kt + 64);
      const u16* As  = sm + cur * QKV_BUF;
      const u16* B0s = As + 128 * 64;
#pragma unroll
      for (int kc = 0; kc < 2; ++kc) {
        int pc = ((kc * 4 + quad) ^ (lr & 7)) * 8;
        bf16x8 af[4], b0f[2];
#pragma unroll
        for (int i = 0; i < 4; ++i) af[i] = *(const bf16x8*)&As[(wm + i * 16 + lr) * 64 + pc];
#pragma unroll
        for (int j = 0; j < 2; ++j) b0f[j] = *(const bf16x8*)&B0s[(wn + j * 16 + lr) * 64 + pc];
#pragma unroll
        for (int mi = 0; mi < 4; ++mi)
#pragma unroll
          for (int ni = 0; ni < 2; ++ni)
            acc[mi][ni] = __builtin_amdgcn_mfma_f32_16x16x32_bf16(af[mi], b0f[ni], acc[mi][ni], 0, 0, 0);
      }
      drain_vm_barrier();
      cur ^= 1;
    }
#pragma unroll
    for (int mi = 0; mi < 4; ++mi)
#pragma unroll
      for (int ni = 0; ni < 2; ++ni) {
        int col = n0 + wn + ni * 16 + lr;
        float bb_ = bq[col];
        int row0 = m0 + wm + mi * 16 + quad * 4;
#pragma unroll
        for (int r = 0; r < 4; ++r)
          Qb[(size_t)(row0 + r) * DIM + col] = f2bf((acc[mi][ni][r] + bb_) * QSCALE);
      }
  }
}

// ---------------- 128x64 GEMM, dbuf+overlap, fp32 out + bias + residual (O proj) ----
#define O_BUF 12288  // u16 per buffer: (128+64)*64
__global__ __launch_bounds__(256) void gemm_o(const u16* __restrict__ A,
    const u16* __restrict__ Bt, const float* __restrict__ bias,
    float* __restrict__ out, const float* __restrict__ resid) {
  __shared__ __align__(16) u16 sm[2 * O_BUF];  // 48 KB
  int tid = threadIdx.x, wave = tid >> 6, lane = tid & 63;
  int lr = lane & 15, quad = lane >> 4;
  int m0 = blockIdx.x * 128, n0 = blockIdx.y * 64;
  int wm = (wave >> 1) * 64, wn = (wave & 1) * 32;

  auto stage = [&](int buf, int kt) {
    u16* As = sm + buf * O_BUF;
    u16* Bs = As + 128 * 64;
#pragma unroll
    for (int r = 0; r < 4; ++r) {
      int slot = tid + r * 256;
      int row = slot >> 3;
      int c = (slot & 7) ^ (row & 7);
      gld16(A + (size_t)(m0 + row) * DIM + kt + c * 8, &As[slot * 8]);
    }
#pragma unroll
    for (int r = 0; r < 2; ++r) {
      int slot = tid + r * 256;
      int row = slot >> 3;
      int c = (slot & 7) ^ (row & 7);
      gld16(Bt + (size_t)(n0 + row) * DIM + kt + c * 8, &Bs[slot * 8]);
    }
  };

  f32x4 acc[4][2] = {};
  stage(0, 0);
  drain_vm_barrier();
  int cur = 0;
  for (int kt = 0; kt < DIM; kt += 64) {
    if (kt + 64 < DIM) stage(cur ^ 1, kt + 64);
    const u16* As = sm + cur * O_BUF;
    const u16* Bs = As + 128 * 64;
#pragma unroll
    for (int kc = 0; kc < 2; ++kc) {
      int pc = ((kc * 4 + quad) ^ (lr & 7)) * 8;
      bf16x8 af[4], bfr[2];
#pragma unroll
      for (int i = 0; i < 4; ++i) af[i] = *(const bf16x8*)&As[(wm + i * 16 + lr) * 64 + pc];
#pragma unroll
      for (int j = 0; j < 2; ++j) bfr[j] = *(const bf16x8*)&Bs[(wn + j * 16 + lr) * 64 + pc];
#pragma unroll
      for (int mi = 0; mi < 4; ++mi)
#pragma unroll
        for (int ni = 0; ni < 2; ++ni)
          acc[mi][ni] = __builtin_amdgcn_mfma_f32_16x16x32_bf16(af[mi], bfr[ni], acc[mi][ni], 0, 0, 0);
    }
    drain_vm_barrier();
    cur ^= 1;
  }
#pragma unroll
  for (int mi = 0; mi < 4; ++mi)
#pragma unroll
    for (int ni = 0; ni < 2; ++ni) {
      int col = n0 + wn + ni * 16 + lr;
      float bv = bias[col];
      int row0 = m0 + wm + mi * 16 + quad * 4;
#pragma unroll
      for (int r = 0; r < 4; ++r) {
        int row = row0 + r;
        out[(size_t)row * DIM + col] = acc[mi][ni][r] + bv + resid[(size_t)row * DIM + col];
      }
    }
}

// ---------------- Flash attention, LDS-FREE: K/V fragments direct from L1/L2 ------
// Per (b,h): K panel 256KB, V panel 256KB -> L2-resident; per-tile working set 16KB
// -> L1-resident across the 8 fragment loads per tile (each 128B line fully consumed).
// No LDS, no barriers, no swizzle: waves fully independent. kA/kB double-buffered
// K-fragments (static names); V loaded per half, latency hidden under QK+softmax.
__global__ __launch_bounds__(256) void flash_kernel(const u16* __restrict__ Q,
    const u16* __restrict__ Kg, const u16* __restrict__ Vt, u16* __restrict__ AO) {
  int tid = threadIdx.x, wave = tid >> 6, lane = tid & 63;
  int ln = lane & 31, hi = lane >> 5;
  int bh = blockIdx.x, b = bh >> 4, h = bh & 15;
  int q0 = blockIdx.y * 128;

  // Q B-fragments (one-time): col q = ln, d = ds*16 + hi*8 + {0..7}
  size_t qrow = (size_t)(b * 2048 + q0 + wave * 32 + ln);
  bf16x8 qf[4];
#pragma unroll
  for (int ds = 0; ds < 4; ++ds)
    qf[ds] = *(const bf16x8*)&Q[qrow * DIM + h * HD + ds * 16 + hi * 8];

  // fragment base pointers (lane-resolved)
  // K frag (tile j, kt2, ds): row tok = j*64 + kt2*32 + ln, d = ds*16 + hi*8
  const u16* kb = Kg + ((size_t)(b * 2048 + ln)) * DIM + h * HD + hi * 8;
  // V frag (tile j, dt, kk): row ch = dt*32 + ln, tok = j*64 + kk*16 + hi*8
  const u16* vb = Vt + ((size_t)(b * 1024 + h * HD + ln)) * 2048 + hi * 8;

#define LOADK(dst, j)                                                          \
  _Pragma("unroll")                                                            \
  for (int kt2 = 0; kt2 < 2; ++kt2)                                            \
    _Pragma("unroll")                                                          \
    for (int ds = 0; ds < 4; ++ds)                                             \
      dst[kt2 * 4 + ds] = *(const bf16x8*)(kb + ((size_t)((j) * 64 + kt2 * 32)) * DIM + ds * 16);

#define LOADV(dst, j)                                                          \
  _Pragma("unroll")                                                            \
  for (int dt = 0; dt < 2; ++dt)                                               \
    _Pragma("unroll")                                                          \
    for (int kk = 0; kk < 4; ++kk)                                             \
      dst[dt * 4 + kk] = *(const bf16x8*)(vb + (size_t)(dt * 32) * 2048 + (j) * 64 + kk * 16);

  float plsum = 0.f;
  f32x16 oacc[2] = {};
  bf16x8 kA[8], kB[8], vC[8];

  LOADK(kA, 0);

#define HALF(KCUR, KNXT, jj, jnxt)                                             \
  {                                                                            \
    LOADV(vC, jj);                                                             \
    if ((jnxt) < 32) LOADK(KNXT, jnxt);                                        \
    f32x16 sf[2] = {};                                                         \
    __builtin_amdgcn_s_setprio(1);                                             \
    _Pragma("unroll")                                                          \
    for (int kt2 = 0; kt2 < 2; ++kt2)                                          \
      _Pragma("unroll")                                                        \
      for (int ds = 0; ds < 4; ++ds)                                           \
        sf[kt2] = __builtin_amdgcn_mfma_f32_32x32x16_bf16(KCUR[kt2 * 4 + ds], qf[ds], sf[kt2], 0, 0, 0); \
    __builtin_amdgcn_s_setprio(0);                                             \
    bf16x8 pb[4];                                                              \
    _Pragma("unroll")                                                          \
    for (int kt2 = 0; kt2 < 2; ++kt2)                                          \
      _Pragma("unroll")                                                        \
      for (int ks = 0; ks < 2; ++ks) {                                         \
        float e0 = fexp2(sf[kt2][ks * 8 + 0]), e1 = fexp2(sf[kt2][ks * 8 + 1]);\
        float e2 = fexp2(sf[kt2][ks * 8 + 2]), e3 = fexp2(sf[kt2][ks * 8 + 3]);\
        float e4 = fexp2(sf[kt2][ks * 8 + 4]), e5 = fexp2(sf[kt2][ks * 8 + 5]);\
        float e6 = fexp2(sf[kt2][ks * 8 + 6]), e7 = fexp2(sf[kt2][ks * 8 + 7]);\
        plsum += ((e0 + e1) + (e2 + e3)) + ((e4 + e5) + (e6 + e7));            \
        unsigned w0 = pk2(e0, e1), w1 = pk2(e2, e3);                           \
        unsigned w2 = pk2(e4, e5), w3 = pk2(e6, e7);                           \
        pl32swap(w0, w2);                                                      \
        pl32swap(w1, w3);                                                      \
        u32x4 t; t.x = w0; t.y = w1; t.z = w2; t.w = w3;                       \
        pb[kt2 * 2 + ks] = __builtin_bit_cast(bf16x8, t);                      \
      }                                                                        \
    __builtin_amdgcn_s_setprio(1);                                             \
    _Pragma("unroll")                                                          \
    for (int dt = 0; dt < 2; ++dt)                                             \
      _Pragma("unroll")                                                        \
      for (int kk = 0; kk < 4; ++kk)                                           \
        oacc[dt] = __builtin_amdgcn_mfma_f32_32x32x16_bf16(vC[dt * 4 + kk], pb[kk], oacc[dt], 0, 0, 0); \
    __builtin_amdgcn_s_setprio(0);                                             \
  }

  for (int j = 0; j < 32; j += 2) {
    HALF(kA, kB, j, j + 1);
    HALF(kB, kA, j + 1, j + 2);
  }
#undef HALF
#undef LOADK
#undef LOADV

  // lanes i and i+32 hold the same q (col = lane&31), disjoint d halves.
  // Normalize in f32 and write final AO (no combine pass).
  float l = plsum + __shfl_xor(plsum, 32, 64);
  float rl = 1.f / l;
#pragma unroll
  for (int dt = 0; dt < 2; ++dt)
#pragma unroll
    for (int g = 0; g < 4; ++g) {  // regs g*4+{0..3} -> d = dt*32 + g*8 + hi*4 + {0..3}
      uint2 pk;
      pk.x = pk2(oacc[dt][g * 4 + 0] * rl, oacc[dt][g * 4 + 1] * rl);
      pk.y = pk2(oacc[dt][g * 4 + 2] * rl, oacc[dt][g * 4 + 3] * rl);
      *(uint2*)&AO[qrow * DIM + h * HD + dt * 32 + g * 8 + hi * 4] = pk;
    }
}

extern "C" void kernel_launch(void* const* d_in, const int* in_sizes, int n_in,
                              void* d_out, int out_size, void* d_ws, size_t ws_size,
                              hipStream_t stream) {
  const float* query   = (const float*)d_in[0];
  const float* context = (const float*)d_in[1];
  const float* Wq = (const float*)d_in[2];
  const float* bq = (const float*)d_in[3];
  const float* Wk = (const float*)d_in[4];
  const float* bk = (const float*)d_in[5];
  const float* Wv = (const float*)d_in[6];
  const float* bv = (const float*)d_in[7];
  const float* Wo = (const float*)d_in[8];
  const float* bo = (const float*)d_in[9];
  const float* gq    = (const float*)d_in[10];
  const float* betaq = (const float*)d_in[11];
  const float* gkv   = (const float*)d_in[12];
  const float* betakv= (const float*)d_in[13];
  (void)in_sizes; (void)n_in; (void)out_size; (void)ws_size;

  char* ws = (char*)d_ws;
  const size_t MB = (size_t)1 << 20;
  u16* qn  = (u16*)(ws + 0 * MB);   // dead after QKV gemm
  u16* cn  = (u16*)(ws + 8 * MB);   // dead after QKV gemm
  u16* Wqt = (u16*)(ws + 16 * MB);  // dead after QKV
  u16* Wkt = (u16*)(ws + 18 * MB);
  u16* Wvt = (u16*)(ws + 20 * MB);
  u16* Wot = (u16*)(ws + 22 * MB);  // alive until O proj
  u16* Qb  = (u16*)(ws + 24 * MB);
  u16* Kb  = (u16*)(ws + 32 * MB);
  u16* Vtb = (u16*)(ws + 40 * MB);
  u16* AOb = (u16*)(ws + 48 * MB);

  prep_kernel<<<12288, 256, 0, stream>>>(query, context, gq, betaq, gkv, betakv,
                                         qn, cn, Wq, Wk, Wv, Wo, Wqt, Wkt, Wvt, Wot);

  gemm_qkv<<<dim3(32, 16, 2), 256, 0, stream>>>(qn, cn, Wqt, Wkt, Wvt,
                                                bq, bk, bv, Qb, Kb, Vtb);

  flash_kernel<<<dim3(32, 16), 256, 0, stream>>>(Qb, Kb, Vtb, AOb);

  gemm_o<<<dim3(32, 16), 256, 0, stream>>>(AOb, Wot, bo, (float*)d_out, query);
}

// Round 13
// 200.342 us; speedup vs baseline: 1.3747x; 1.3747x over previous
//
#include <hip/hip_runtime.h>
#include <hip/hip_bf16.h>

typedef unsigned short u16;
typedef unsigned long long u64;
typedef __bf16 bf16x8 __attribute__((ext_vector_type(8)));
typedef float f32x4 __attribute__((ext_vector_type(4)));
typedef float f32x16 __attribute__((ext_vector_type(16)));
typedef unsigned u32x4 __attribute__((ext_vector_type(4)));

#define DIM 1024
#define NH 16
#define HD 64
// 0.125 * log2(e): folds the 1/sqrt(64) score scale and the exp->exp2 change of base
#define QSCALE 0.180336880972788f

__device__ __forceinline__ u16 f2bf(float f) {
  union { float f; unsigned u; } v; v.f = f;
  unsigned r = v.u + 0x7fffu + ((v.u >> 16) & 1u);
  return (u16)(r >> 16);
}

__device__ __forceinline__ unsigned pk2(float a, float b) {
  union { __hip_bfloat162 h; unsigned u; } cv;
  cv.h = __float22bfloat162_rn(make_float2(a, b));
  return cv.u;
}

__device__ __forceinline__ float bf2f(unsigned s) {
  union { unsigned u; float f; } v; v.u = s << 16; return v.f;
}

__device__ __forceinline__ float fexp2(float x) {
#if __has_builtin(__builtin_amdgcn_exp2f)
  return __builtin_amdgcn_exp2f(x);   // raw v_exp_f32, no OCML denormal fixup
#else
  return exp2f(x);
#endif
}

__device__ __forceinline__ void gld16(const u16* gp, u16* lp) {
  __builtin_amdgcn_global_load_lds(
      (const __attribute__((address_space(1))) unsigned int*)(const void*)gp,
      (__attribute__((address_space(3))) unsigned int*)(void*)lp, 16, 0, 0);
}

// swap: a.hi-lanes <-> b.lo-lanes.  After: a = {lo: a, hi: b[lane-32]}, b = {lo: a[lane+32], hi: b}
__device__ __forceinline__ void pl32swap(unsigned& a, unsigned& b) {
  asm volatile("v_permlane32_swap_b32 %0, %1" : "+v"(a), "+v"(b));
}

__device__ __forceinline__ void drain_vm_barrier() {
  // counted-drain of our prefetch, then RAW barrier (no compiler-injected full drain)
  asm volatile("s_waitcnt vmcnt(0)" ::: "memory");
  __builtin_amdgcn_s_barrier();
}

// ---------------- Fused prep: 2x LayerNorm + 4x weight transpose ----------------
__global__ __launch_bounds__(256) void prep_kernel(
    const float* __restrict__ q, const float* __restrict__ c,
    const float* __restrict__ gq, const float* __restrict__ bq,
    const float* __restrict__ gkv, const float* __restrict__ bkv,
    u16* __restrict__ qn, u16* __restrict__ cn,
    const float* W0, const float* W1, const float* W2, const float* W3,
    u16* O0, u16* O1, u16* O2, u16* O3) {
  __shared__ float red[2][4];
  __shared__ float t[32][33];
  int bid = blockIdx.x, tid = threadIdx.x;
  if (bid < 8192) {
    const float* x  = bid < 4096 ? q : c;
    const float* g  = bid < 4096 ? gq : gkv;
    const float* be = bid < 4096 ? bq : bkv;
    u16* out = bid < 4096 ? qn : cn;
    int row = bid & 4095;
    float4 v = ((const float4*)(x + (size_t)row * DIM))[tid];
    float s1 = v.x + v.y + v.z + v.w;
    float s2 = v.x * v.x + v.y * v.y + v.z * v.z + v.w * v.w;
#pragma unroll
    for (int o = 32; o >= 1; o >>= 1) { s1 += __shfl_xor(s1, o, 64); s2 += __shfl_xor(s2, o, 64); }
    int wv = tid >> 6;
    if ((tid & 63) == 0) { red[0][wv] = s1; red[1][wv] = s2; }
    __syncthreads();
    s1 = red[0][0] + red[0][1] + red[0][2] + red[0][3];
    s2 = red[1][0] + red[1][1] + red[1][2] + red[1][3];
    float mu = s1 * (1.f / DIM);
    float var = s2 * (1.f / DIM) - mu * mu;
    float rs = rsqrtf(var + 1e-5f);
    float4 gv = ((const float4*)g)[tid];
    float4 bv = ((const float4*)be)[tid];
    uint2 o2;
    o2.x = pk2((v.x - mu) * rs * gv.x + bv.x, (v.y - mu) * rs * gv.y + bv.y);
    o2.y = pk2((v.z - mu) * rs * gv.z + bv.z, (v.w - mu) * rs * gv.w + bv.w);
    ((uint2*)(out + (size_t)row * DIM))[tid] = o2;
  } else {
    int wid = bid - 8192;
    int z = wid >> 10;
    const float* W = z == 0 ? W0 : z == 1 ? W1 : z == 2 ? W2 : W3;
    u16* O        = z == 0 ? O0 : z == 1 ? O1 : z == 2 ? O2 : O3;
    int xy = wid & 1023;
    int bx = (xy & 31) * 32, by = (xy >> 5) * 32;
    int tx = tid & 31, ty = tid >> 5;
#pragma unroll
    for (int i = 0; i < 4; ++i) t[ty + i * 8][tx] = W[(size_t)(by + ty + i * 8) * DIM + bx + tx];
    __syncthreads();
#pragma unroll
    for (int i = 0; i < 4; ++i) O[(size_t)(bx + ty + i * 8) * DIM + by + tx] = f2bf(t[tx][ty + i * 8]);
  }
}

// ---------------- QKV projections: z=0 fused K+V (shared A tile), z=1 Q ----------------
// Double-buffered LDS (2x32KB) + prefetch-overlap: STAGE(t+1) issued BEFORE compute(t),
// single vmcnt(0)+raw-barrier per K-tile (T3-minimum). Round-2 epilogues.
#define QKV_BUF 16384  // u16 per buffer: (128+64+64)*64
__global__ __launch_bounds__(256) void gemm_qkv(
    const u16* __restrict__ qn, const u16* __restrict__ cn,
    const u16* __restrict__ Wqt, const u16* __restrict__ Wkt, const u16* __restrict__ Wvt,
    const float* __restrict__ bq, const float* __restrict__ bk, const float* __restrict__ bv,
    u16* __restrict__ Qb, u16* __restrict__ Kb, u16* __restrict__ Vtb) {
  __shared__ __align__(16) u16 sm[2 * QKV_BUF];  // 64 KB
  int tid = threadIdx.x, wave = tid >> 6, lane = tid & 63;
  int lr = lane & 15, quad = lane >> 4;
  int m0 = blockIdx.x * 128, n0 = blockIdx.y * 64;
  int wm = (wave >> 1) * 64, wn = (wave & 1) * 32;

  if (blockIdx.z == 0) {
    // ---- K + V fused over A = cn ----
    auto stage = [&](int buf, int kt) {
      u16* As  = sm + buf * QKV_BUF;
      u16* B0s = As + 128 * 64;
      u16* B1s = As + 192 * 64;
#pragma unroll
      for (int r = 0; r < 4; ++r) {
        int slot = tid + r * 256;
        int row = slot >> 3;
        int c = (slot & 7) ^ (row & 7);
        gld16(cn + (size_t)(m0 + row) * DIM + kt + c * 8, &As[slot * 8]);
      }
#pragma unroll
      for (int r = 0; r < 2; ++r) {
        int slot = tid + r * 256;
        int row = slot >> 3;
        int c = (slot & 7) ^ (row & 7);
        gld16(Wkt + (size_t)(n0 + row) * DIM + kt + c * 8, &B0s[slot * 8]);
        gld16(Wvt + (size_t)(n0 + row) * DIM + kt + c * 8, &B1s[slot * 8]);
      }
    };

    f32x4 acck[4][2] = {}, accv[4][2] = {};
    stage(0, 0);
    drain_vm_barrier();
    int cur = 0;
    for (int kt = 0; kt < DIM; kt += 64) {
      if (kt + 64 < DIM) stage(cur ^ 1, kt + 64);
      const u16* As  = sm + cur * QKV_BUF;
      const u16* B0s = As + 128 * 64;
      const u16* B1s = As + 192 * 64;
#pragma unroll
      for (int kc = 0; kc < 2; ++kc) {
        int pc = ((kc * 4 + quad) ^ (lr & 7)) * 8;
        bf16x8 af[4], b0f[2], b1f[2];
#pragma unroll
        for (int i = 0; i < 4; ++i) af[i] = *(const bf16x8*)&As[(wm + i * 16 + lr) * 64 + pc];
#pragma unroll
        for (int j = 0; j < 2; ++j) {
          b0f[j] = *(const bf16x8*)&B0s[(wn + j * 16 + lr) * 64 + pc];
          b1f[j] = *(const bf16x8*)&B1s[(wn + j * 16 + lr) * 64 + pc];
        }
#pragma unroll
        for (int mi = 0; mi < 4; ++mi)
#pragma unroll
          for (int ni = 0; ni < 2; ++ni) {
            acck[mi][ni] = __builtin_amdgcn_mfma_f32_16x16x32_bf16(af[mi], b0f[ni], acck[mi][ni], 0, 0, 0);
            accv[mi][ni] = __builtin_amdgcn_mfma_f32_16x16x32_bf16(b1f[ni], af[mi], accv[mi][ni], 0, 0, 0);
          }
      }
      drain_vm_barrier();
      cur ^= 1;
    }
    // K epilogue: row-major
#pragma unroll
    for (int mi = 0; mi < 4; ++mi)
#pragma unroll
      for (int ni = 0; ni < 2; ++ni) {
        int col = n0 + wn + ni * 16 + lr;
        float bb_ = bk[col];
        int row0 = m0 + wm + mi * 16 + quad * 4;
#pragma unroll
        for (int r = 0; r < 4; ++r)
          Kb[(size_t)(row0 + r) * DIM + col] = f2bf(acck[mi][ni][r] + bb_);
      }
    // V epilogue: accv = C^T (col=token m via lr, row=channel n via quad*4+r)
#pragma unroll
    for (int mi = 0; mi < 4; ++mi) {
      int m = m0 + wm + mi * 16 + lr;
      int bb = m >> 11, tt = m & 2047;
      u16* outb = Vtb + (((size_t)bb << 10)) * 2048 + tt;
#pragma unroll
      for (int ni = 0; ni < 2; ++ni) {
        int nbase = n0 + wn + ni * 16 + quad * 4;
#pragma unroll
        for (int r = 0; r < 4; ++r)
          outb[(size_t)(nbase + r) * 2048] = f2bf(accv[mi][ni][r] + bv[nbase + r]);
      }
    }
  } else {
    // ---- Q over A = qn ----
    auto stage = [&](int buf, int kt) {
      u16* As  = sm + buf * QKV_BUF;
      u16* B0s = As + 128 * 64;
#pragma unroll
      for (int r = 0; r < 4; ++r) {
        int slot = tid + r * 256;
        int row = slot >> 3;
        int c = (slot & 7) ^ (row & 7);
        gld16(qn + (size_t)(m0 + row) * DIM + kt + c * 8, &As[slot * 8]);
      }
#pragma unroll
      for (int r = 0; r < 2; ++r) {
        int slot = tid + r * 256;
        int row = slot >> 3;
        int c = (slot & 7) ^ (row & 7);
        gld16(Wqt + (size_t)(n0 + row) * DIM + kt + c * 8, &B0s[slot * 8]);
      }
    };

    f32x4 acc[4][2] = {};
    stage(0, 0);
    drain_vm_barrier();
    int cur = 0;
    for (int kt = 0; kt < DIM; kt += 64) {
      if (kt + 64 < DIM) stage(cur ^ 1, kt + 64);
      const u16* As  = sm + cur * QKV_BUF;
      const u16* B0s = As + 128 * 64;
#pragma unroll
      for (int kc = 0; kc < 2; ++kc) {
        int pc = ((kc * 4 + quad) ^ (lr & 7)) * 8;
        bf16x8 af[4], b0f[2];
#pragma unroll
        for (int i = 0; i < 4; ++i) af[i] = *(const bf16x8*)&As[(wm + i * 16 + lr) * 64 + pc];
#pragma unroll
        for (int j = 0; j < 2; ++j) b0f[j] = *(const bf16x8*)&B0s[(wn + j * 16 + lr) * 64 + pc];
#pragma unroll
        for (int mi = 0; mi < 4; ++mi)
#pragma unroll
          for (int ni = 0; ni < 2; ++ni)
            acc[mi][ni] = __builtin_amdgcn_mfma_f32_16x16x32_bf16(af[mi], b0f[ni], acc[mi][ni], 0, 0, 0);
      }
      drain_vm_barrier();
      cur ^= 1;
    }
#pragma unroll
    for (int mi = 0; mi < 4; ++mi)
#pragma unroll
      for (int ni = 0; ni < 2; ++ni) {
        int col = n0 + wn + ni * 16 + lr;
        float bb_ = bq[col];
        int row0 = m0 + wm + mi * 16 + quad * 4;
#pragma unroll
        for (int r = 0; r < 4; ++r)
          Qb[(size_t)(row0 + r) * DIM + col] = f2bf((acc[mi][ni][r] + bb_) * QSCALE);
      }
  }
}

// ---------------- 128x64 GEMM, dbuf+overlap, fp32 out + bias + residual (O proj) ----
#define O_BUF 12288  // u16 per buffer: (128+64)*64
__global__ __launch_bounds__(256) void gemm_o(const u16* __restrict__ A,
    const u16* __restrict__ Bt, const float* __restrict__ bias,
    float* __restrict__ out, const float* __restrict__ resid) {
  __shared__ __align__(16) u16 sm[2 * O_BUF];  // 48 KB
  int tid = threadIdx.x, wave = tid >> 6, lane = tid & 63;
  int lr = lane & 15, quad = lane >> 4;
  int m0 = blockIdx.x * 128, n0 = blockIdx.y * 64;
  int wm = (wave >> 1) * 64, wn = (wave & 1) * 32;

  auto stage = [&](int buf, int kt) {
    u16* As = sm + buf * O_BUF;
    u16* Bs = As + 128 * 64;
#pragma unroll
    for (int r = 0; r < 4; ++r) {
      int slot = tid + r * 256;
      int row = slot >> 3;
      int c = (slot & 7) ^ (row & 7);
      gld16(A + (size_t)(m0 + row) * DIM + kt + c * 8, &As[slot * 8]);
    }
#pragma unroll
    for (int r = 0; r < 2; ++r) {
      int slot = tid + r * 256;
      int row = slot >> 3;
      int c = (slot & 7) ^ (row & 7);
      gld16(Bt + (size_t)(n0 + row) * DIM + kt + c * 8, &Bs[slot * 8]);
    }
  };

  f32x4 acc[4][2] = {};
  stage(0, 0);
  drain_vm_barrier();
  int cur = 0;
  for (int kt = 0; kt < DIM; kt += 64) {
    if (kt + 64 < DIM) stage(cur ^ 1, kt + 64);
    const u16* As = sm + cur * O_BUF;
    const u16* Bs = As + 128 * 64;
#pragma unroll
    for (int kc = 0; kc < 2; ++kc) {
      int pc = ((kc * 4 + quad) ^ (lr & 7)) * 8;
      bf16x8 af[4], bfr[2];
#pragma unroll
      for (int i = 0; i < 4; ++i) af[i] = *(const bf16x8*)&As[(wm + i * 16 + lr) * 64 + pc];
#pragma unroll
      for (int j = 0; j < 2; ++j) bfr[j] = *(const bf16x8*)&Bs[(wn + j * 16 + lr) * 64 + pc];
#pragma unroll
      for (int mi = 0; mi < 4; ++mi)
#pragma unroll
        for (int ni = 0; ni < 2; ++ni)
          acc[mi][ni] = __builtin_amdgcn_mfma_f32_16x16x32_bf16(af[mi], bfr[ni], acc[mi][ni], 0, 0, 0);
    }
    drain_vm_barrier();
    cur ^= 1;
  }
#pragma unroll
  for (int mi = 0; mi < 4; ++mi)
#pragma unroll
    for (int ni = 0; ni < 2; ++ni) {
      int col = n0 + wn + ni * 16 + lr;
      float bv = bias[col];
      int row0 = m0 + wm + mi * 16 + quad * 4;
#pragma unroll
      for (int r = 0; r < 4; ++r) {
        int row = row0 + r;
        out[(size_t)row * DIM + col] = acc[mi][ni][r] + bv + resid[(size_t)row * DIM + col];
      }
    }
}

// ---------------- Flash attention, NO split-K, 64KB LDS 4-deep, 32x32x16 MFMA ------
// Q,K: [B*2048,1024] bf16 (Q pre-scaled). Vt: [(b*1024+h*64+d)][token] bf16.
// LDS u16: K bufs 4x4096 @0, V bufs 4x4096 @16384. 32 j-tiles of 64 tokens.
// Barrier every 2 tiles; prefetch 2 tiles ahead (bufs j+2,j+3 vs reads j,j+1 - disjoint mod 4).
// Epilogue normalizes by 1/l in f32 and writes final bf16 AO (combine kernel eliminated).
__global__ __launch_bounds__(256, 2) void flash_kernel(const u16* __restrict__ Q,
    const u16* __restrict__ Kg, const u16* __restrict__ Vt, u16* __restrict__ AO) {
  __shared__ __align__(16) u16 lds[32768];  // 64 KB
  int tid = threadIdx.x, wave = tid >> 6, lane = tid & 63;
  int ln = lane & 31, hi = lane >> 5;
  int bh = blockIdx.x, b = bh >> 4, h = bh & 15;
  int q0 = blockIdx.y * 128;

  const u16* kbase = Kg + (size_t)(b * 2048) * DIM + h * HD;
  const u16* vbase = Vt + (size_t)(b * 1024 + h * HD) * 2048;

  // Q B-fragments (one-time, from global): col q = ln, d = ds*16 + hi*8 + {0..7}
  size_t qrow = (size_t)(b * 2048 + q0 + wave * 32 + ln);
  bf16x8 qf[4];
#pragma unroll
  for (int ds = 0; ds < 4; ++ds)
    qf[ds] = *(const bf16x8*)&Q[qrow * DIM + h * HD + ds * 16 + hi * 8];

  // strength-reduced staging pointers (advance 1 tile = 64 tokens per stage call)
  int slot0 = tid, slot1 = tid + 256;
  int r0 = slot0 >> 3, c0 = (slot0 & 7) ^ (r0 & 7);
  int r1 = slot1 >> 3, c1 = (slot1 & 7) ^ (r1 & 7);
  const u16* kp0 = kbase + (size_t)r0 * DIM + c0 * 8;
  const u16* kp1 = kbase + (size_t)r1 * DIM + c1 * 8;
  const u16* vp0 = vbase + (size_t)r0 * 2048 + c0 * 8;
  const u16* vp1 = vbase + (size_t)r1 * 2048 + c1 * 8;

  // prologue: stage tiles 0,1 into bufs 0,1
#pragma unroll
  for (int t = 0; t < 2; ++t) {
    gld16(kp0, &lds[t * 4096 + slot0 * 8]);
    gld16(kp1, &lds[t * 4096 + slot1 * 8]);
    gld16(vp0, &lds[16384 + t * 4096 + slot0 * 8]);
    gld16(vp1, &lds[16384 + t * 4096 + slot1 * 8]);
    kp0 += 64 * DIM; kp1 += 64 * DIM; vp0 += 64; vp1 += 64;
  }
  drain_vm_barrier();

  float plsum = 0.f;
  f32x16 oacc[2] = {};

  for (int j = 0; j < 32; j += 2) {
    // prefetch tiles j+2, j+3 into bufs (j+2)&3, (j+3)&3 (disjoint from read bufs j&3,(j+1)&3)
    if (j + 2 < 32) {
#pragma unroll
      for (int t = 0; t < 2; ++t) {
        int bi = (j + 2 + t) & 3;
        gld16(kp0, &lds[bi * 4096 + slot0 * 8]);
        gld16(kp1, &lds[bi * 4096 + slot1 * 8]);
        gld16(vp0, &lds[16384 + bi * 4096 + slot0 * 8]);
        gld16(vp1, &lds[16384 + bi * 4096 + slot1 * 8]);
        kp0 += 64 * DIM; kp1 += 64 * DIM; vp0 += 64; vp1 += 64;
      }
    }

#pragma unroll
    for (int jj = 0; jj < 2; ++jj) {
      int bi = (j + jj) & 3;
      const u16* kcb = &lds[bi * 4096];
      const u16* vcb = &lds[16384 + bi * 4096];

      // S^T[kt2] (32 ktok x 32 q) = sum_ds mfma32x32x16(K_frag, qf[ds])
      f32x16 sf[2] = {};
      __builtin_amdgcn_s_setprio(1);
#pragma unroll
      for (int kt2 = 0; kt2 < 2; ++kt2) {
        int rs = (kt2 * 32 + ln) * 64;
        int rx = (kt2 * 32 + ln) & 7;
#pragma unroll
        for (int ds = 0; ds < 4; ++ds) {
          bf16x8 kf = *(const bf16x8*)&kcb[rs + (((ds * 2 + hi) ^ rx) * 8)];
          sf[kt2] = __builtin_amdgcn_mfma_f32_32x32x16_bf16(kf, qf[ds], sf[kt2], 0, 0, 0);
        }
      }
      __builtin_amdgcn_s_setprio(0);

      // p = exp2(s); PV B-fragments in-register (cvt_pk + permlane32_swap, T12)
      bf16x8 pb[4];
#pragma unroll
      for (int kt2 = 0; kt2 < 2; ++kt2)
#pragma unroll
        for (int ks = 0; ks < 2; ++ks) {
          float e0 = fexp2(sf[kt2][ks * 8 + 0]), e1 = fexp2(sf[kt2][ks * 8 + 1]);
          float e2 = fexp2(sf[kt2][ks * 8 + 2]), e3 = fexp2(sf[kt2][ks * 8 + 3]);
          float e4 = fexp2(sf[kt2][ks * 8 + 4]), e5 = fexp2(sf[kt2][ks * 8 + 5]);
          float e6 = fexp2(sf[kt2][ks * 8 + 6]), e7 = fexp2(sf[kt2][ks * 8 + 7]);
          plsum += ((e0 + e1) + (e2 + e3)) + ((e4 + e5) + (e6 + e7));
          unsigned w0 = pk2(e0, e1), w1 = pk2(e2, e3);
          unsigned w2 = pk2(e4, e5), w3 = pk2(e6, e7);
          pl32swap(w0, w2);   // -> B0, B2
          pl32swap(w1, w3);   // -> B1, B3
          u32x4 t; t.x = w0; t.y = w1; t.z = w2; t.w = w3;
          pb[kt2 * 2 + ks] = __builtin_bit_cast(bf16x8, t);
        }

      // O^T[dt] (32 d x 32 q) += V^T . P^T over 4 k-steps of 16
      __builtin_amdgcn_s_setprio(1);
#pragma unroll
      for (int dt = 0; dt < 2; ++dt) {
        int rs = (dt * 32 + ln) * 64;
        int rx = (dt * 32 + ln) & 7;
#pragma unroll
        for (int kk = 0; kk < 4; ++kk) {
          bf16x8 vf = *(const bf16x8*)&vcb[rs + (((kk * 2 + hi) ^ rx) * 8)];
          oacc[dt] = __builtin_amdgcn_mfma_f32_32x32x16_bf16(vf, pb[kk], oacc[dt], 0, 0, 0);
        }
      }
      __builtin_amdgcn_s_setprio(0);
    }
    drain_vm_barrier();
  }

  // lanes i and i+32 hold the same q (col = lane&31), disjoint d halves.
  // Normalize in f32 and write final AO (no combine pass).
  float l = plsum + __shfl_xor(plsum, 32, 64);
  float rl = 1.f / l;
#pragma unroll
  for (int dt = 0; dt < 2; ++dt)
#pragma unroll
    for (int g = 0; g < 4; ++g) {  // regs g*4+{0..3} -> d = dt*32 + g*8 + hi*4 + {0..3}
      uint2 pk;
      pk.x = pk2(oacc[dt][g * 4 + 0] * rl, oacc[dt][g * 4 + 1] * rl);
      pk.y = pk2(oacc[dt][g * 4 + 2] * rl, oacc[dt][g * 4 + 3] * rl);
      *(uint2*)&AO[qrow * DIM + h * HD + dt * 32 + g * 8 + hi * 4] = pk;
    }
}

extern "C" void kernel_launch(void* const* d_in, const int* in_sizes, int n_in,
                              void* d_out, int out_size, void* d_ws, size_t ws_size,
                              hipStream_t stream) {
  const float* query   = (const float*)d_in[0];
  const float* context = (const float*)d_in[1];
  const float* Wq = (const float*)d_in[2];
  const float* bq = (const float*)d_in[3];
  const float* Wk = (const float*)d_in[4];
  const float* bk = (const float*)d_in[5];
  const float* Wv = (const float*)d_in[6];
  const float* bv = (const float*)d_in[7];
  const float* Wo = (const float*)d_in[8];
  const float* bo = (const float*)d_in[9];
  const float* gq    = (const float*)d_in[10];
  const float* betaq = (const float*)d_in[11];
  const float* gkv   = (const float*)d_in[12];
  const float* betakv= (const float*)d_in[13];
  (void)in_sizes; (void)n_in; (void)out_size; (void)ws_size;

  char* ws = (char*)d_ws;
  const size_t MB = (size_t)1 << 20;
  u16* qn  = (u16*)(ws + 0 * MB);   // dead after QKV gemm
  u16* cn  = (u16*)(ws + 8 * MB);   // dead after QKV gemm
  u16* Wqt = (u16*)(ws + 16 * MB);  // dead after QKV
  u16* Wkt = (u16*)(ws + 18 * MB);
  u16* Wvt = (u16*)(ws + 20 * MB);
  u16* Wot = (u16*)(ws + 22 * MB);  // alive until O proj
  u16* Qb  = (u16*)(ws + 24 * MB);
  u16* Kb  = (u16*)(ws + 32 * MB);
  u16* Vtb = (u16*)(ws + 40 * MB);
  u16* AOb = (u16*)(ws + 48 * MB);

  prep_kernel<<<12288, 256, 0, stream>>>(query, context, gq, betaq, gkv, betakv,
                                         qn, cn, Wq, Wk, Wv, Wo, Wqt, Wkt, Wvt, Wot);

  gemm_qkv<<<dim3(32, 16, 2), 256, 0, stream>>>(qn, cn, Wqt, Wkt, Wvt,
                                                bq, bk, bv, Qb, Kb, Vtb);

  flash_kernel<<<dim3(32, 16), 256, 0, stream>>>(Qb, Kb, Vtb, AOb);

  gemm_o<<<dim3(32, 16), 256, 0, stream>>>(AOb, Wot, bo, (float*)d_out, query);
}